// Round 5
// baseline (146.665 us; speedup 1.0000x reference)
//
#include <hip/hip_runtime.h>

// FAVOR+ causal linear attention — fused single kernel with hand-rolled grid
// barrier (grid=256 blocks = 1/CU, co-residency structurally guaranteed).
// BH=8, D=DV=64, N=2048, M=128, chunk C=32, NCH=64; block owns 2 chunks,
// 2 waves per chunk.
// Phase A: phiQ^T(LDS), phiK^T(LDS), phiK(LDS), S_c^T->ws, z_c->ws,
//          masked Amat(LDS), norm_intra(LDS), Y_intra -> REGISTERS.
// gbar -> Phase B: exclusive prefix scan of S^T (bf16) + z (f32) over chunks.
// gbar -> Phase C: acc += phiQ^T.S_excl; out = acc / (normI + phiQ^T.z_excl).

#define BH 8
#define DD 64
#define DV 64
#define NSEQ 2048
#define MM 128
#define CK 32
#define NCH 64
#define NBLK 256
#define PHI_SCALE 0.08838834764831845f

typedef unsigned int uint;
typedef unsigned short ushort;
typedef __attribute__((ext_vector_type(8))) short bf16x8;
typedef __attribute__((ext_vector_type(4))) float f32x4;
#define MFMA16(a, b, c) __builtin_amdgcn_mfma_f32_16x16x32_bf16((a), (b), (c), 0, 0, 0)

__device__ __forceinline__ short f2bf(float x) {
    uint u = __float_as_uint(x);
    u += 0x7fffu + ((u >> 16) & 1u);
    return (short)(u >> 16);
}
__device__ __forceinline__ float bf2f(ushort b) {
    return __uint_as_float(((uint)b) << 16);
}

// ws layout (bytes): St bf16 [BH][NCH][64][128] 8MB | z f32 [BH][NCH][128] 256KB
//                    | Fb bf16 [128][64] 16KB | barrier uints
#define OFF_Z   8388608u
#define OFF_FB  8650752u
#define OFF_BAR 8667136u

// ---- init: zero barrier counters, convert F to bf16 ----
__global__ __launch_bounds__(256) void favor_init(
    const float* __restrict__ features, ushort* __restrict__ Fb,
    uint* __restrict__ bar)
{
    const int tid = threadIdx.x;
    if (tid < 32) bar[tid] = 0u;
    uint* fo = (uint*)Fb;
    const float2* fi = (const float2*)features;
    for (int i = tid; i < 4096; i += 256) {
        float2 f = fi[i];
        fo[i] = (uint)(ushort)f2bf(f.x) | ((uint)(ushort)f2bf(f.y) << 16);
    }
}

// hand grid barrier: all NBLK blocks guaranteed resident (1 block/CU)
__device__ __forceinline__ void gbar(uint* cnt)
{
    __syncthreads();                      // drains each wave's vmcnt to L2
    if (threadIdx.x == 0) {
        __threadfence();                  // XCD L2 writeback (release)
        __hip_atomic_fetch_add(cnt, 1u, __ATOMIC_ACQ_REL, __HIP_MEMORY_SCOPE_AGENT);
        while (__hip_atomic_load(cnt, __ATOMIC_ACQUIRE, __HIP_MEMORY_SCOPE_AGENT) < NBLK) {}
        __threadfence();                  // invalidate (acquire)
    }
    __syncthreads();
}

__global__ __launch_bounds__(256, 2) void favor_main(
    const float* __restrict__ keys, const float* __restrict__ values,
    const float* __restrict__ queries, const ushort* __restrict__ Fb,
    ushort* __restrict__ St, float* __restrict__ z, uint* __restrict__ bar,
    float* __restrict__ out)
{
    const int b = blockIdx.x;                    // 256 blocks
    const int bh = b >> 5, pr_ = b & 31;         // head, chunk-pair
    const int tid = threadIdx.x;
    const int lane = tid & 63, wid = tid >> 6, quad = lane >> 4, l16 = lane & 15;
    const int ch = wid >> 1, sw = wid & 1;       // chunk-in-pair, n-subtile
    const int ck = 2 * pr_ + ch, n0c = ck * CK;

    __shared__ __align__(16) char sm[60672];
    short* sPQT = (short*)sm;                    // [2][32][136] PERSISTS  17408
    short* sPKT = (short*)(sm + 17408);          // [2][32][136] phase A   17408
    short* sPK  = (short*)(sm + 34816);          // [2][128][40] phase A   20480
    short* sAm  = (short*)(sm + 55296);          // [2][32][40]  phase A    5120
    float* sNI  = (float*)(sm + 60416);          // [2][32]      PERSISTS    256
    // phase-C aliases over dead phase-A scratch:
    float* sOut = (float*)(sm + 17408);          // [2][32][66]           16896
    float* sPart= (float*)(sm + 34816);          // [2][32][4]             1024
    float* sNm  = (float*)(sm + 36352);          // [2][32]                 256

    short* pqt = sPQT + ch * 4352;
    short* pkt = sPKT + ch * 4352;
    short* ppk = sPK + ch * 5120;

    // ---- Phase A ----
    for (int i = tid; i < 1280; i += 256) ((uint*)sAm)[i] = 0u;  // zero Amat

    // phi A-frag gathers (fp32 columns, this wave's n-tile)
    {
        const float* Qb = queries + (size_t)(bh * DD) * NSEQ + n0c + 16 * sw + l16;
        const float* Kb = keys    + (size_t)(bh * DD) * NSEQ + n0c + 16 * sw + l16;
        bf16x8 aQ[2], aK[2];
        for (int h = 0; h < 2; ++h)
            for (int j = 0; j < 8; ++j) {
                const int d = 32 * h + 8 * quad + j;
                aQ[h][j] = f2bf(Qb[(size_t)d * NSEQ]);
                aK[h][j] = f2bf(Kb[(size_t)d * NSEQ]);
            }
        for (int mt = 0; mt < 8; ++mt) {
            f32x4 accQ = {0.f, 0.f, 0.f, 0.f}, accK = {0.f, 0.f, 0.f, 0.f};
            for (int h = 0; h < 2; ++h) {
                bf16x8 bF = *(const bf16x8*)(Fb + (16 * mt + l16) * 64 + 32 * h + 8 * quad);
                accQ = MFMA16(aQ[h], bF, accQ);
                accK = MFMA16(aK[h], bF, accK);
            }
            for (int r = 0; r < 4; ++r) {
                const int nl = 16 * sw + 4 * quad + r, m = 16 * mt + l16;
                pqt[nl * 136 + m] = f2bf(fmaxf(accQ[r], 0.f) * PHI_SCALE);
                const short pk = f2bf(fmaxf(accK[r], 0.f) * PHI_SCALE);
                pkt[nl * 136 + m] = pk;
                ppk[m * 40 + nl] = pk;
            }
        }
    }
    __syncthreads();  // B0

    // z_c[m] = sum_n phiK[m][n]  (tid-based, both chunks; rotated for banks)
    {
        const int zch = tid >> 7, m = tid & 127;
        const short* pp = sPK + zch * 5120 + m * 40;
        float s = 0.f;
        for (int n = 0; n < CK; ++n) s += bf2f((ushort)pp[(n + m) & 31]);
        z[(size_t)(bh * NCH + 2 * pr_ + zch) * MM + m] = s;
    }

    // S_c^T[v][m] = sum_n V[v][n] phiK[m][n]  (V A-frags from global fp32)
    {
        ushort* So = St + (size_t)(bh * NCH + ck) * (DV * MM);
        const float* Vb = values + (size_t)(bh * DV) * NSEQ + n0c;
        for (int t = 0; t < 2; ++t) {
            const int vt = 2 * sw + t;
            const float4* vp = (const float4*)(Vb + (size_t)(16 * vt + l16) * NSEQ + 8 * quad);
            float4 v0 = vp[0], v1 = vp[1];
            bf16x8 aV;
            aV[0] = f2bf(v0.x); aV[1] = f2bf(v0.y); aV[2] = f2bf(v0.z); aV[3] = f2bf(v0.w);
            aV[4] = f2bf(v1.x); aV[5] = f2bf(v1.y); aV[6] = f2bf(v1.z); aV[7] = f2bf(v1.w);
            for (int mt = 0; mt < 8; ++mt) {
                bf16x8 bP = *(const bf16x8*)(ppk + (16 * mt + l16) * 40 + 8 * quad);
                f32x4 acc = {0.f, 0.f, 0.f, 0.f};
                acc = MFMA16(aV, bP, acc);
                for (int r = 0; r < 4; ++r)
                    So[(16 * vt + 4 * quad + r) * MM + 16 * mt + l16] = (ushort)f2bf(acc[r]);
            }
        }
    }

    // Amat[n][j] (causal) + norm_intra rowsums; only jt <= sw tiles are nonzero
    {
        float rs[4] = {0.f, 0.f, 0.f, 0.f};
        for (int jt = 0; jt <= sw; ++jt) {
            f32x4 acc = {0.f, 0.f, 0.f, 0.f};
            for (int mc = 0; mc < 4; ++mc) {
                bf16x8 aP = *(const bf16x8*)(pqt + (16 * sw + l16) * 136 + 32 * mc + 8 * quad);
                bf16x8 bP = *(const bf16x8*)(pkt + (16 * jt + l16) * 136 + 32 * mc + 8 * quad);
                acc = MFMA16(aP, bP, acc);
            }
            for (int r = 0; r < 4; ++r) {
                const int nl = 16 * sw + 4 * quad + r, jl = 16 * jt + l16;
                const float av = (jl <= nl) ? acc[r] : 0.f;
                rs[r] += av;
                sAm[ch * 1280 + nl * 40 + jl] = f2bf(av);
            }
        }
        for (int r = 0; r < 4; ++r) {
            float s = rs[r];
            s += __shfl_xor(s, 1); s += __shfl_xor(s, 2);
            s += __shfl_xor(s, 4); s += __shfl_xor(s, 8);
            if (l16 == 0) sNI[ch * 32 + 16 * sw + 4 * quad + r] = s;
        }
    }

    // Y_intra[n][v] = Amat . V  -> registers (same wave wrote its sAm rows)
    f32x4 acc[4];
    {
        bf16x8 aA = *(const bf16x8*)(sAm + ch * 1280 + (16 * sw + l16) * 40 + 8 * quad);
        const float* Vb = values + (size_t)(bh * DV) * NSEQ + n0c;
        for (int vt = 0; vt < 4; ++vt) {
            const float4* vp = (const float4*)(Vb + (size_t)(16 * vt + l16) * NSEQ + 8 * quad);
            float4 v0 = vp[0], v1 = vp[1];
            bf16x8 bV;
            bV[0] = f2bf(v0.x); bV[1] = f2bf(v0.y); bV[2] = f2bf(v0.z); bV[3] = f2bf(v0.w);
            bV[4] = f2bf(v1.x); bV[5] = f2bf(v1.y); bV[6] = f2bf(v1.z); bV[7] = f2bf(v1.w);
            acc[vt] = (f32x4){0.f, 0.f, 0.f, 0.f};
            acc[vt] = MFMA16(aA, bV, acc[vt]);
        }
    }

    // ---- Phase B: grid barrier, then exclusive prefix scans ----
    gbar(bar + 0);
    {
        const int gid = b * 256 + tid;               // exactly 65536 S^T columns
        const int sbh = gid >> 13, vm = gid & 8191;
        ushort* p = St + (size_t)sbh * (NCH * 8192) + vm;
        float run = 0.f;
        for (int half = 0; half < 2; ++half) {
            float vals[32];
            #pragma unroll
            for (int cc = 0; cc < 32; ++cc) vals[cc] = bf2f(p[(size_t)(32 * half + cc) * 8192]);
            #pragma unroll
            for (int cc = 0; cc < 32; ++cc) {
                p[(size_t)(32 * half + cc) * 8192] = (ushort)f2bf(run);
                run += vals[cc];
            }
        }
        if (b < 4) {                                 // 1024 z columns
            const int zc = b * 256 + tid;
            const int zbh = zc >> 7, m = zc & 127;
            float* pz = z + (size_t)zbh * (NCH * MM) + m;
            float zr = 0.f;
            for (int half = 0; half < 2; ++half) {
                float zv[32];
                #pragma unroll
                for (int cc = 0; cc < 32; ++cc) zv[cc] = pz[(32 * half + cc) * MM];
                #pragma unroll
                for (int cc = 0; cc < 32; ++cc) {
                    pz[(32 * half + cc) * MM] = zr;
                    zr += zv[cc];
                }
            }
        }
    }
    gbar(bar + 1);

    // ---- Phase C ----
    // acc += phiQ^T . S_excl
    {
        const ushort* sb = St + (size_t)(bh * NCH + ck) * 8192;
        bf16x8 aP[4];
        for (int mc = 0; mc < 4; ++mc)
            aP[mc] = *(const bf16x8*)(pqt + (16 * sw + l16) * 136 + 32 * mc + 8 * quad);
        for (int vt = 0; vt < 4; ++vt)
            for (int mc = 0; mc < 4; ++mc) {
                bf16x8 bS = *(const bf16x8*)(sb + (16 * vt + l16) * MM + 32 * mc + 8 * quad);
                acc[vt] = MFMA16(aP[mc], bS, acc[vt]);
            }
    }
    // norm = normI + phiQ^T . z_excl
    {
        const int nch = tid >> 7, t2 = tid & 127, n = t2 >> 2, seg = t2 & 3;
        const uint* pr2 = (const uint*)(sPQT + nch * 4352) + n * 68 + seg * 16;
        const float* zz = z + (size_t)(bh * NCH + 2 * pr_ + nch) * MM + seg * 32;
        float s = 0.f;
        #pragma unroll
        for (int k = 0; k < 16; ++k) {
            const uint u = pr2[k];
            s += bf2f((ushort)(u & 0xffffu)) * zz[2 * k];
            s += bf2f((ushort)(u >> 16)) * zz[2 * k + 1];
        }
        sPart[nch * 128 + n * 4 + seg] = s;
    }
    __syncthreads();
    if (tid < 64) {
        const int nch = tid >> 5, n = tid & 31;
        float nm = sNI[nch * 32 + n];
        #pragma unroll
        for (int s4 = 0; s4 < 4; ++s4) nm += sPart[nch * 128 + n * 4 + s4];
        sNm[nch * 32 + n] = nm;
    }
    __syncthreads();
    // divide + transpose-stage
    for (int vt = 0; vt < 4; ++vt)
        for (int r = 0; r < 4; ++r) {
            const int nl = 16 * sw + 4 * quad + r, v = 16 * vt + l16;
            sOut[ch * 2112 + nl * 66 + v] = acc[vt][r] / sNm[ch * 32 + nl];
        }
    __syncthreads();
    // coalesced store (lanes along n)
    for (int i = tid; i < 4096; i += 256) {
        const int och = i >> 11, rem = i & 2047, v = rem >> 5, n = rem & 31;
        out[(size_t)(bh * DV + v) * NSEQ + (2 * pr_ + och) * CK + n] =
            sOut[och * 2112 + n * 66 + v];
    }
}

extern "C" void kernel_launch(void* const* d_in, const int* in_sizes, int n_in,
                              void* d_out, int out_size, void* d_ws, size_t ws_size,
                              hipStream_t stream)
{
    (void)in_sizes; (void)n_in; (void)out_size; (void)ws_size;
    const float* keys     = (const float*)d_in[0];
    const float* values   = (const float*)d_in[1];
    const float* queries  = (const float*)d_in[2];
    const float* features = (const float*)d_in[3];
    float* outp = (float*)d_out;

    char* ws = (char*)d_ws;
    ushort* St = (ushort*)ws;
    float*  z  = (float*)(ws + OFF_Z);
    ushort* Fb = (ushort*)(ws + OFF_FB);
    uint*   bar = (uint*)(ws + OFF_BAR);

    favor_init<<<dim3(1), dim3(256), 0, stream>>>(features, Fb, bar);
    favor_main<<<dim3(NBLK), dim3(256), 0, stream>>>(keys, values, queries, Fb,
                                                     St, z, bar, outp);
}

// Round 6
// 104.081 us; speedup vs baseline: 1.4091x; 1.4091x over previous
//
#include <hip/hip_runtime.h>

// FAVOR+ causal linear attention — fused kernel, hand-rolled RELAXED grid
// barrier (no cache-flush fences). Cross-barrier data (St, z) goes through
// the MALL via relaxed agent-scope atomics (sc1: bypasses non-coherent XCD
// L2s). grid=256 blocks = 1/CU -> co-residency structurally guaranteed.
// Block owns 2 chunks (C=32), 2 waves per chunk.
// Phase A: phiQ^T(LDS), phiK^T(LDS), phiK(LDS), S_c^T->ws(sc1), z_c->ws(sc1),
//          masked Amat(LDS), norm_intra(LDS), Y_intra -> registers.
// gbar -> Phase B: exclusive prefix scan of S^T (uint cols) + z over chunks.
// gbar -> Phase C: acc += phiQ^T.S_excl; out = acc / (normI + phiQ^T.z_excl).

#define BH 8
#define DD 64
#define DV 64
#define NSEQ 2048
#define MM 128
#define CK 32
#define NCH 64
#define NBLK 256
#define PHI_SCALE 0.08838834764831845f

typedef unsigned int uint;
typedef unsigned short ushort;
typedef unsigned long long ulong64;
typedef __attribute__((ext_vector_type(8))) short bf16x8;
typedef __attribute__((ext_vector_type(4))) float f32x4;
#define MFMA16(a, b, c) __builtin_amdgcn_mfma_f32_16x16x32_bf16((a), (b), (c), 0, 0, 0)

__device__ __forceinline__ short f2bf(float x) {
    uint u = __float_as_uint(x);
    u += 0x7fffu + ((u >> 16) & 1u);
    return (short)(u >> 16);
}
__device__ __forceinline__ float bf2f(ushort b) {
    return __uint_as_float(((uint)b) << 16);
}

#define AST(p, v)  __hip_atomic_store((p), (v), __ATOMIC_RELAXED, __HIP_MEMORY_SCOPE_AGENT)
#define ALD(p)     __hip_atomic_load((p), __ATOMIC_RELAXED, __HIP_MEMORY_SCOPE_AGENT)

// ws layout: St bf16 [BH][NCH][64][128] 8MB | z f32 [BH][NCH][128] 256KB | bar
#define OFF_Z   8388608u
#define OFF_BAR 8650752u

// relaxed grid barrier: no fences, no cache flushes. Data ordering comes from
// __syncthreads' vmcnt(0) drain (sc1 stores complete at MALL before arrival).
__device__ __forceinline__ void gbar(uint* cnt)
{
    __syncthreads();
    if (threadIdx.x == 0) {
        __hip_atomic_fetch_add(cnt, 1u, __ATOMIC_RELAXED, __HIP_MEMORY_SCOPE_AGENT);
        while (__hip_atomic_load(cnt, __ATOMIC_RELAXED, __HIP_MEMORY_SCOPE_AGENT) < NBLK)
            __builtin_amdgcn_s_sleep(4);
    }
    __syncthreads();
}

__global__ __launch_bounds__(256, 2) void favor_main(
    const float* __restrict__ keys, const float* __restrict__ values,
    const float* __restrict__ queries, const float* __restrict__ features,
    ushort* St, float* z, uint* bar, float* __restrict__ out)
{
    const int b = blockIdx.x;                    // 256 blocks
    const int bh = b >> 5, pr_ = b & 31;         // head, chunk-pair
    const int tid = threadIdx.x;
    const int lane = tid & 63, wid = tid >> 6, quad = lane >> 4, l16 = lane & 15;
    const int ch = wid >> 1, sw = wid & 1;       // chunk-in-pair, n-subtile
    const int ck = 2 * pr_ + ch, n0c = ck * CK;

    __shared__ __align__(16) char sm[60672];
    short* sPQT = (short*)sm;                    // [2][32][136] PERSISTS  17408
    short* sPKT = (short*)(sm + 17408);          // [2][32][136] phase A   17408
    short* sPK  = (short*)(sm + 34816);          // [2][128][40] phase A   20480
    short* sAm  = (short*)(sm + 55296);          // [2][32][40]  phase A    5120
    float* sNI  = (float*)(sm + 60416);          // [2][32]      PERSISTS    256
    // phase-C aliases over dead phase-A scratch:
    float* sOut = (float*)(sm + 17408);          // [2][32][66]           16896
    float* sPart= (float*)(sm + 34816);          // [2][32][4]             1024
    float* sNm  = (float*)(sm + 36352);          // [2][32]                 256
    float* sZ   = (float*)(sm + 36608);          // [2][128]               1024

    short* pqt = sPQT + ch * 4352;
    short* pkt = sPKT + ch * 4352;
    short* ppk = sPK + ch * 5120;

    // ---- Phase A ----
    for (int i = tid; i < 1280; i += 256) ((uint*)sAm)[i] = 0u;  // zero Amat

    // phi: Q/K A-frag gathers (fp32 columns); F B-frags from global fp32
    {
        const float* Qb = queries + (size_t)(bh * DD) * NSEQ + n0c + 16 * sw + l16;
        const float* Kb = keys    + (size_t)(bh * DD) * NSEQ + n0c + 16 * sw + l16;
        bf16x8 aQ[2], aK[2];
        for (int h = 0; h < 2; ++h)
            for (int j = 0; j < 8; ++j) {
                const int d = 32 * h + 8 * quad + j;
                aQ[h][j] = f2bf(Qb[(size_t)d * NSEQ]);
                aK[h][j] = f2bf(Kb[(size_t)d * NSEQ]);
            }
        for (int mt = 0; mt < 8; ++mt) {
            f32x4 accQ = {0.f, 0.f, 0.f, 0.f}, accK = {0.f, 0.f, 0.f, 0.f};
            for (int h = 0; h < 2; ++h) {
                const float4* fp = (const float4*)(features + (16 * mt + l16) * 64 + 32 * h + 8 * quad);
                float4 f0 = fp[0], f1 = fp[1];
                bf16x8 bF;
                bF[0] = f2bf(f0.x); bF[1] = f2bf(f0.y); bF[2] = f2bf(f0.z); bF[3] = f2bf(f0.w);
                bF[4] = f2bf(f1.x); bF[5] = f2bf(f1.y); bF[6] = f2bf(f1.z); bF[7] = f2bf(f1.w);
                accQ = MFMA16(aQ[h], bF, accQ);
                accK = MFMA16(aK[h], bF, accK);
            }
            for (int r = 0; r < 4; ++r) {
                const int nl = 16 * sw + 4 * quad + r, m = 16 * mt + l16;
                pqt[nl * 136 + m] = f2bf(fmaxf(accQ[r], 0.f) * PHI_SCALE);
                const short pk = f2bf(fmaxf(accK[r], 0.f) * PHI_SCALE);
                pkt[nl * 136 + m] = pk;
                ppk[m * 40 + nl] = pk;
            }
        }
    }
    __syncthreads();  // B0

    // z_c[m] = sum_n phiK[m][n]  (sc1 store)
    {
        const int zch = tid >> 7, m = tid & 127;
        const short* pp = sPK + zch * 5120 + m * 40;
        float s = 0.f;
        for (int n = 0; n < CK; ++n) s += bf2f((ushort)pp[(n + m) & 31]);
        AST(&z[(size_t)(bh * NCH + 2 * pr_ + zch) * MM + m], s);
    }

    // S_c^T[v][m] = sum_n V[v][n] phiK[m][n]  (sc1 scattered bf16 stores)
    {
        ushort* So = St + (size_t)(bh * NCH + ck) * (DV * MM);
        const float* Vb = values + (size_t)(bh * DV) * NSEQ + n0c;
        for (int t = 0; t < 2; ++t) {
            const int vt = 2 * sw + t;
            const float4* vp = (const float4*)(Vb + (size_t)(16 * vt + l16) * NSEQ + 8 * quad);
            float4 v0 = vp[0], v1 = vp[1];
            bf16x8 aV;
            aV[0] = f2bf(v0.x); aV[1] = f2bf(v0.y); aV[2] = f2bf(v0.z); aV[3] = f2bf(v0.w);
            aV[4] = f2bf(v1.x); aV[5] = f2bf(v1.y); aV[6] = f2bf(v1.z); aV[7] = f2bf(v1.w);
            for (int mt = 0; mt < 8; ++mt) {
                bf16x8 bP = *(const bf16x8*)(ppk + (16 * mt + l16) * 40 + 8 * quad);
                f32x4 acc = {0.f, 0.f, 0.f, 0.f};
                acc = MFMA16(aV, bP, acc);
                for (int r = 0; r < 4; ++r)
                    AST(&So[(16 * vt + 4 * quad + r) * MM + 16 * mt + l16],
                        (ushort)f2bf(acc[r]));
            }
        }
    }

    // Amat[n][j] (causal) + norm_intra rowsums; only jt <= sw tiles nonzero
    {
        float rs[4] = {0.f, 0.f, 0.f, 0.f};
        for (int jt = 0; jt <= sw; ++jt) {
            f32x4 acc = {0.f, 0.f, 0.f, 0.f};
            for (int mc = 0; mc < 4; ++mc) {
                bf16x8 aP = *(const bf16x8*)(pqt + (16 * sw + l16) * 136 + 32 * mc + 8 * quad);
                bf16x8 bP = *(const bf16x8*)(pkt + (16 * jt + l16) * 136 + 32 * mc + 8 * quad);
                acc = MFMA16(aP, bP, acc);
            }
            for (int r = 0; r < 4; ++r) {
                const int nl = 16 * sw + 4 * quad + r, jl = 16 * jt + l16;
                const float av = (jl <= nl) ? acc[r] : 0.f;
                rs[r] += av;
                sAm[ch * 1280 + nl * 40 + jl] = f2bf(av);
            }
        }
        for (int r = 0; r < 4; ++r) {
            float s = rs[r];
            s += __shfl_xor(s, 1); s += __shfl_xor(s, 2);
            s += __shfl_xor(s, 4); s += __shfl_xor(s, 8);
            if (l16 == 0) sNI[ch * 32 + 16 * sw + 4 * quad + r] = s;
        }
    }

    // Y_intra[n][v] = Amat . V  -> registers
    f32x4 acc[4];
    {
        bf16x8 aA = *(const bf16x8*)(sAm + ch * 1280 + (16 * sw + l16) * 40 + 8 * quad);
        const float* Vb = values + (size_t)(bh * DV) * NSEQ + n0c;
        for (int vt = 0; vt < 4; ++vt) {
            const float4* vp = (const float4*)(Vb + (size_t)(16 * vt + l16) * NSEQ + 8 * quad);
            float4 v0 = vp[0], v1 = vp[1];
            bf16x8 bV;
            bV[0] = f2bf(v0.x); bV[1] = f2bf(v0.y); bV[2] = f2bf(v0.z); bV[3] = f2bf(v0.w);
            bV[4] = f2bf(v1.x); bV[5] = f2bf(v1.y); bV[6] = f2bf(v1.z); bV[7] = f2bf(v1.w);
            acc[vt] = (f32x4){0.f, 0.f, 0.f, 0.f};
            acc[vt] = MFMA16(aA, bV, acc[vt]);
        }
    }

    // ---- Phase B: grid barrier, then exclusive prefix scans (all sc1) ----
    gbar(bar + 0);
    if (b < 128) {                       // 32768 uint columns of St
        const int gid = b * 256 + tid;
        const int sbh = gid >> 12, col = gid & 4095;
        uint* p = (uint*)St + (size_t)sbh * (NCH * 4096) + col;
        float rlo = 0.f, rhi = 0.f;
        for (int half = 0; half < 2; ++half) {
            uint v[32];
            #pragma unroll
            for (int cc = 0; cc < 32; ++cc)
                v[cc] = ALD(p + (size_t)(32 * half + cc) * 4096);
            #pragma unroll
            for (int cc = 0; cc < 32; ++cc) {
                const uint ov = (uint)(ushort)f2bf(rlo) | ((uint)(ushort)f2bf(rhi) << 16);
                AST(p + (size_t)(32 * half + cc) * 4096, ov);
                rlo += bf2f((ushort)(v[cc] & 0xffffu));
                rhi += bf2f((ushort)(v[cc] >> 16));
            }
        }
    } else if (b < 132) {                // 1024 z columns
        const int zc = (b - 128) * 256 + tid;
        const int zbh = zc >> 7, m = zc & 127;
        float* pz = z + (size_t)zbh * (NCH * MM) + m;
        float zr = 0.f;
        for (int half = 0; half < 2; ++half) {
            float zv[32];
            #pragma unroll
            for (int cc = 0; cc < 32; ++cc) zv[cc] = ALD(pz + (32 * half + cc) * MM);
            #pragma unroll
            for (int cc = 0; cc < 32; ++cc) {
                AST(pz + (32 * half + cc) * MM, zr);
                zr += zv[cc];
            }
        }
    }
    gbar(bar + 1);

    // ---- Phase C ----
    // stage z_excl to LDS (coalesced sc1 loads)
    {
        const int zch = tid >> 7, m = tid & 127;
        sZ[zch * 128 + m] = ALD(&z[(size_t)(bh * NCH + 2 * pr_ + zch) * MM + m]);
    }
    // acc += phiQ^T . S_excl  (St frags via 8B sc1 loads)
    {
        const ulong64* sb8 = (const ulong64*)(St + (size_t)(bh * NCH + ck) * 8192);
        bf16x8 aP[4];
        for (int mc = 0; mc < 4; ++mc)
            aP[mc] = *(const bf16x8*)(pqt + (16 * sw + l16) * 136 + 32 * mc + 8 * quad);
        for (int vt = 0; vt < 4; ++vt) {
            const int row = 16 * vt + l16;
            for (int mc = 0; mc < 4; ++mc) {
                union { ulong64 u[2]; bf16x8 v; } cvt;
                cvt.u[0] = ALD(sb8 + row * 32 + 8 * mc + 2 * quad);
                cvt.u[1] = ALD(sb8 + row * 32 + 8 * mc + 2 * quad + 1);
                acc[vt] = MFMA16(aP[mc], cvt.v, acc[vt]);
            }
        }
    }
    __syncthreads();
    // norm matvec partials: phiQ^T (LDS) . z_excl (LDS)
    {
        const int nch = tid >> 7, t2 = tid & 127, n = t2 >> 2, seg = t2 & 3;
        const uint* pr2 = (const uint*)(sPQT + nch * 4352) + n * 68 + seg * 16;
        const float* zz = sZ + nch * 128 + seg * 32;
        float s = 0.f;
        #pragma unroll
        for (int k = 0; k < 16; ++k) {
            const uint u = pr2[k];
            s += bf2f((ushort)(u & 0xffffu)) * zz[2 * k];
            s += bf2f((ushort)(u >> 16)) * zz[2 * k + 1];
        }
        sPart[nch * 128 + n * 4 + seg] = s;
    }
    __syncthreads();
    if (tid < 64) {
        const int nch = tid >> 5, n = tid & 31;
        float nm = sNI[nch * 32 + n];
        #pragma unroll
        for (int s4 = 0; s4 < 4; ++s4) nm += sPart[nch * 128 + n * 4 + s4];
        sNm[nch * 32 + n] = nm;
    }
    __syncthreads();
    // divide + transpose-stage
    for (int vt = 0; vt < 4; ++vt)
        for (int r = 0; r < 4; ++r) {
            const int nl = 16 * sw + 4 * quad + r, v = 16 * vt + l16;
            sOut[ch * 2112 + nl * 66 + v] = acc[vt][r] / sNm[ch * 32 + nl];
        }
    __syncthreads();
    // coalesced store (lanes along n)
    for (int i = tid; i < 4096; i += 256) {
        const int och = i >> 11, rem = i & 2047, v = rem >> 5, n = rem & 31;
        out[(size_t)(bh * DV + v) * NSEQ + (2 * pr_ + och) * CK + n] =
            sOut[och * 2112 + n * 66 + v];
    }
}

extern "C" void kernel_launch(void* const* d_in, const int* in_sizes, int n_in,
                              void* d_out, int out_size, void* d_ws, size_t ws_size,
                              hipStream_t stream)
{
    (void)in_sizes; (void)n_in; (void)out_size; (void)ws_size;
    const float* keys     = (const float*)d_in[0];
    const float* values   = (const float*)d_in[1];
    const float* queries  = (const float*)d_in[2];
    const float* features = (const float*)d_in[3];
    float* outp = (float*)d_out;

    char* ws = (char*)d_ws;
    ushort* St  = (ushort*)ws;
    float*  z   = (float*)(ws + OFF_Z);
    uint*   bar = (uint*)(ws + OFF_BAR);

    hipMemsetAsync(bar, 0, 8, stream);   // zero the two barrier counters
    favor_main<<<dim3(NBLK), dim3(256), 0, stream>>>(keys, values, queries,
                                                     features, St, z, bar, outp);
}